// Round 13
// baseline (24.101 us; speedup 1.0000x reference)
//
#include <hip/hip_runtime.h>

#define CC 8
#define HW 4096
#define L2E 1.4426950408889634f

typedef __attribute__((ext_vector_type(4))) float f32x4;
typedef __attribute__((ext_vector_type(2))) float f32x2;

// Full-wave (64-lane) sum reduction on the VALU pipe via DPP (lands in lane 63).
static __device__ __forceinline__ float dpp_sum64(float v) {
#define DPPSTEP(CTRL, RM, BM)                                              \
  v += __int_as_float(__builtin_amdgcn_update_dpp(                         \
      0, __float_as_int(v), CTRL, RM, BM, true));
  DPPSTEP(0x111, 0xf, 0xf)   // row_shr:1
  DPPSTEP(0x112, 0xf, 0xf)   // row_shr:2
  DPPSTEP(0x114, 0xf, 0xe)   // row_shr:4
  DPPSTEP(0x118, 0xf, 0xc)   // row_shr:8
  DPPSTEP(0x142, 0xa, 0xf)   // row_bcast:15
  DPPSTEP(0x143, 0xc, 0xf)   // row_bcast:31
#undef DPPSTEP
  return v;
}

// Packed 2-m PAM step: v_pk_mul (arg) + 2x v_exp + v_pk_add (den) + v_pk_fma (num).
static __device__ __forceinline__ void step2(f32x2 kk, f32x2 vv, f32x2 aa,
                                             f32x2& dd, f32x2& nn) {
  f32x2 arg = aa * kk;                       // v_pk_mul_f32
  f32x2 ee;
  ee[0] = __builtin_amdgcn_exp2f(arg[0]);
  ee[1] = __builtin_amdgcn_exp2f(arg[1]);
  dd += ee;                                  // v_pk_add_f32
  nn = __builtin_elementwise_fma(ee, vv, nn); // v_pk_fma_f32
}

// Single node: 512 blocks (4 batches x 128 tiles of 32 px) x 512 threads.
// R12 kernel with the tile HALVED so 2 blocks co-reside per CU ->
// 16 waves/CU = 4 waves/SIMD (R12 ran 2/SIMD, VALUBusy ~37%, ~65% stall).
// Per-CU work conserved: each block scans all 4096 m for 32 px
// (lane = px(l&31) x m-half(l>>5), 256 m/lane). kv/Gram duplicated (cheap).
// __launch_bounds__(512,4): VGPR cap 128 (need ~96) -- 2 blocks resident.
__global__ __launch_bounds__(512, 4) void kFused(
    const float* __restrict__ x,
    const float* __restrict__ cwq, const float* __restrict__ cbq,
    const float* __restrict__ cwk, const float* __restrict__ cbk,
    const float* __restrict__ cwv, const float* __restrict__ cbv,
    const float* __restrict__ pwq, const float* __restrict__ pbq,
    const float* __restrict__ pwk, const float* __restrict__ pbk,
    const float* __restrict__ pwv, const float* __restrict__ pbv,
    float* __restrict__ out)
{
  const int b = blockIdx.x >> 7;
  const int n0 = (blockIdx.x & 127) * 32;                   // 32-px tile
  const int t = threadIdx.x, ln = t & 63;
  const int wid = __builtin_amdgcn_readfirstlane(t >> 6);   // wave 0..7
  const int px = ln & 31;                                   // pixel-in-tile
  const int mh = ln >> 5;                                   // m-half 0/1

  __shared__ __align__(16) float k2s[HW];                   // 16 KB: pk*log2e
  __shared__ __align__(16) float pvs[HW];                   // 16 KB: pv
  __shared__ float redd[8][64], redn[8][64];                // 4 KB
  __shared__ float gpart[8][44];
  __shared__ float sums[44], Gl[64], Ll[64], Al[64], Mp[64], cvs[8], outp[32];

  const float* xb = x + b * CC * HW;

  // ---- P0a: k2/pv for my 8 m's (m = 8t..8t+7) ----
  f32x4 xa[CC], xc[CC];
  {
    const int m8 = t * 8;
    #pragma unroll
    for (int c = 0; c < CC; ++c) {
      xa[c] = *(const f32x4*)(xb + c * HW + m8);
      xc[c] = *(const f32x4*)(xb + c * HW + m8 + 4);
    }
    f32x4 ka, kb, va, vb;
    #pragma unroll
    for (int j = 0; j < 8; ++j) {
      float kk = pbk[0], vv = pbv[0];
      #pragma unroll
      for (int c = 0; c < CC; ++c) {
        const float xv = (j < 4) ? xa[c][j & 3] : xc[c][j & 3];
        kk = fmaf(pwk[c], xv, kk);
        vv = fmaf(pwv[c], xv, vv);
      }
      kk *= L2E;
      if (j < 4) { ka[j] = kk; va[j] = vv; }
      else       { kb[j & 3] = kk; vb[j & 3] = vv; }
    }
    ((f32x4*)k2s)[t * 2 + 0] = ka;
    ((f32x4*)k2s)[t * 2 + 1] = kb;
    ((f32x4*)pvs)[t * 2 + 0] = va;
    ((f32x4*)pvs)[t * 2 + 1] = vb;
  }

  // ---- P0b: Gram + rowsum partials from the already-loaded registers ----
  {
    float acc[44];
    #pragma unroll
    for (int i = 0; i < 44; ++i) acc[i] = 0.f;
    #pragma unroll
    for (int j = 0; j < 8; ++j) {
      float xv[CC];
      #pragma unroll
      for (int c = 0; c < CC; ++c) xv[c] = (j < 4) ? xa[c][j & 3] : xc[c][j & 3];
      int k = 0;
      #pragma unroll
      for (int c = 0; c < CC; ++c) {
        #pragma unroll
        for (int d = c; d < CC; ++d) { acc[k] = fmaf(xv[c], xv[d], acc[k]); ++k; }
      }
      #pragma unroll
      for (int c = 0; c < CC; ++c) acc[36 + c] += xv[c];
    }
    #pragma unroll
    for (int i = 0; i < 44; ++i) acc[i] = dpp_sum64(acc[i]);
    if (ln == 63) {
      #pragma unroll
      for (int i = 0; i < 44; ++i) gpart[wid][i] = acc[i];   // static idx
    }
  }

  // ---- P0c: pq + xn for pixel n0+px ----
  float xn[CC];
  #pragma unroll
  for (int c = 0; c < CC; ++c) xn[c] = xb[c * HW + n0 + px];
  float a = pbq[0];
  #pragma unroll
  for (int c = 0; c < CC; ++c) a = fmaf(pwq[c], xn[c], a);

  __syncthreads();

  // ---- P2: PAM direct; lane (px, mh) of wave wid scans 256 m's ----
  {
    const f32x4* kp = ((const f32x4*)k2s) + (wid << 7) + (mh << 6);
    const f32x4* vp = ((const f32x4*)pvs) + (wid << 7) + (mh << 6);
    f32x2 aa; aa[0] = a; aa[1] = a;
    f32x2 z; z[0] = 0.f; z[1] = 0.f;
    f32x2 dA = z, dB = z, nA = z, nB = z;
    #pragma unroll 4
    for (int i = 0; i < 64; ++i) {                          // 4 m per iter
      const f32x4 k4 = kp[i], v4 = vp[i];
      f32x2 kk, vv;
      kk[0] = k4[0]; kk[1] = k4[1]; vv[0] = v4[0]; vv[1] = v4[1];
      step2(kk, vv, aa, dA, nA);
      kk[0] = k4[2]; kk[1] = k4[3]; vv[0] = v4[2]; vv[1] = v4[3];
      step2(kk, vv, aa, dB, nB);
    }
    const f32x2 dS = dA + dB;
    const f32x2 nS = nA + nB;
    redd[wid][ln] = dS[0] + dS[1];
    redn[wid][ln] = nS[0] + nS[1];
  }
  __syncthreads();

  // ---- P3: wave 0: PAM combine + Gram total + CAM 8x8 softmax ----
  if (t < 32) {
    float D = 0.f, N = 0.f;
    #pragma unroll
    for (int s = 0; s < 8; ++s) {
      D += redd[s][t] + redd[s][t + 32];
      N += redn[s][t] + redn[s][t + 32];
    }
    outp[t] = N / D;
  }
  if (t < 44) {
    float s = 0.f;
    #pragma unroll
    for (int w = 0; w < 8; ++w) s += gpart[w][t];
    sums[t] = s;
  }
  __syncthreads();

  const int c = ln >> 3, d = ln & 7;
  if (t < 64) {
    const int lo = min(c, d), hi = max(c, d);
    Gl[t] = sums[lo * 8 + hi - lo * (lo + 1) / 2];
  }
  __syncthreads();

  float Lv = 0.f;
  if (t < 64) {
    float qs = 0.f, ks = 0.f;
    #pragma unroll
    for (int e = 0; e < 8; ++e) {
      qs = fmaf(cwq[c * 8 + e], sums[36 + e], qs);
      ks = fmaf(cwk[d * 8 + e], sums[36 + e], ks);
    }
    float A = 0.f;
    #pragma unroll
    for (int e = 0; e < 8; ++e) {
      float inner = 0.f;
      #pragma unroll
      for (int f = 0; f < 8; ++f) inner = fmaf(Gl[e * 8 + f], cwk[d * 8 + f], inner);
      A = fmaf(cwq[c * 8 + e], inner, A);
    }
    Lv = A + qs * cbk[d] + cbq[c] * ks + 4096.f * cbq[c] * cbk[d];
    Ll[t] = Lv;
  }
  __syncthreads();

  if (t < 64) {
    float mx = -INFINITY;
    #pragma unroll
    for (int f = 0; f < 8; ++f) mx = fmaxf(mx, Ll[c * 8 + f]);
    float ssum = 0.f;
    #pragma unroll
    for (int f = 0; f < 8; ++f) ssum += __expf(Ll[c * 8 + f] - mx);
    Al[t] = __expf(Lv - mx) / ssum;
  }
  __syncthreads();

  if (t < 64) {
    float M = 0.f;
    #pragma unroll
    for (int f = 0; f < 8; ++f) M = fmaf(Al[c * 8 + f], cwv[f * 8 + d], M);
    if (d == c) M += 2.f;            // +2I: residual x appears in both CAM and PAM
    Mp[t] = M;
    if (d == 0) {
      float cvv = 0.f;
      #pragma unroll
      for (int f = 0; f < 8; ++f) cvv = fmaf(Al[c * 8 + f], cbv[f], cvv);
      cvs[c] = cvv;
    }
  }
  __syncthreads();

  // ---- P4: epilogue, t<256: ch = t>>5, pixel n0 + (t&31) ----
  if (t < 256) {
    const int ch = t >> 5, p = t & 31;
    float o = cvs[ch] + outp[p];
    #pragma unroll
    for (int dd = 0; dd < 8; ++dd) o = fmaf(Mp[ch * 8 + dd], xn[dd], o);
    out[(b * 8 + ch) * HW + n0 + p] = o;
  }
}

extern "C" void kernel_launch(void* const* d_in, const int* in_sizes, int n_in,
                              void* d_out, int out_size, void* d_ws, size_t ws_size,
                              hipStream_t stream) {
  const float* x   = (const float*)d_in[0];
  const float* cwq = (const float*)d_in[1];
  const float* cbq = (const float*)d_in[2];
  const float* cwk = (const float*)d_in[3];
  const float* cbk = (const float*)d_in[4];
  const float* cwv = (const float*)d_in[5];
  const float* cbv = (const float*)d_in[6];
  const float* pwq = (const float*)d_in[7];
  const float* pbq = (const float*)d_in[8];
  const float* pwk = (const float*)d_in[9];
  const float* pbk = (const float*)d_in[10];
  const float* pwv = (const float*)d_in[11];
  const float* pbv = (const float*)d_in[12];
  float* out = (float*)d_out;

  hipLaunchKernelGGL(kFused, dim3(512), dim3(512), 0, stream,
                     x, cwq, cbq, cwk, cbk, cwv, cbv,
                     pwq, pbq, pwk, pbk, pwv, pbv, out);
}